// Round 1
// 305.625 us; speedup vs baseline: 1.0084x; 1.0084x over previous
//
#include <hip/hip_runtime.h>
#include <hip/hip_bf16.h>

// ---------------------------------------------------------------------------
// AdaptiveEmbedding: 3-cluster adaptive input embedding.
//   ids in [0,20000)      -> emb0[id] (1024), padding row 0 is zero
//   ids in [20000,60000)  -> proj1(1024x256) @ emb1[id-20000]
//   ids in [60000,128000) -> proj2(1024x64)  @ emb2[id-60000]
// Scaled by sqrt(1024)=32. Each out row written exactly once.
//
// R3 -> R4: counters showed the poison-fill hitting 6.5 TB/s while our 170 MB
// of algorithmic traffic took 308 us (~0.55 TB/s effective). The three
// consumer kernels are each occupancy-starved (gemm c1: 320 active blocks =
// 1.25/CU; c2: 544; copy_c0 latency-bound) and run SERIALLY. Fix: fuse
// copy_c0 + gemm1 + gemm2 into ONE grid-stride kernel over a runtime
// work-list (gemm tiles first = long poles, copy pairs after), so the three
// latency-bound phases overlap and the machine stays full.
// ---------------------------------------------------------------------------

typedef __attribute__((ext_vector_type(4))) float        float4v;
typedef __attribute__((ext_vector_type(8))) short        short8;
typedef __attribute__((ext_vector_type(2))) unsigned int uint2v;

#define D_MODEL 1024

__device__ __forceinline__ short f2bf(float x) {
    // round-to-nearest-even f32 -> bf16 (inputs are finite)
    unsigned u = __builtin_bit_cast(unsigned, x);
    unsigned r = u + 0x7fffu + ((u >> 16) & 1u);
    return (short)(r >> 16);
}

__device__ __forceinline__ short8 cvt8(float4v a, float4v b) {
    short8 r;
    r[0] = f2bf(a[0]); r[1] = f2bf(a[1]); r[2] = f2bf(a[2]); r[3] = f2bf(a[3]);
    r[4] = f2bf(b[0]); r[5] = f2bf(b[1]); r[6] = f2bf(b[2]); r[7] = f2bf(b[3]);
    return r;
}

__device__ __forceinline__ uint2v pack4(float4v v) {
    uint2v r;
    r[0] = (unsigned)(unsigned short)f2bf(v[0]) | ((unsigned)(unsigned short)f2bf(v[1]) << 16);
    r[1] = (unsigned)(unsigned short)f2bf(v[2]) | ((unsigned)(unsigned short)f2bf(v[3]) << 16);
    return r;
}

// ------------------ partition (3 lists) + proj->bf16 conversion -------------
// blocks [0, pb)            : wave-aggregated partition of ids into l0/l1/l2
// blocks [pb, pb+256)       : proj1 (1024x256 fp32) -> bf16, 1 float4/thread
// blocks [pb+256, pb+320)   : proj2 (1024x64  fp32) -> bf16
__global__ __launch_bounds__(256)
void prep_k(const int* __restrict__ ids, int n, int pb,
            int* __restrict__ cnt,
            int* __restrict__ l0, int* __restrict__ l1, int* __restrict__ l2,
            const float* __restrict__ proj1, const float* __restrict__ proj2,
            uint2v* __restrict__ p1bf, uint2v* __restrict__ p2bf)
{
    const int b = blockIdx.x;
    if (b >= pb) {
        if (b < pb + 256) {
            int t = (b - pb) * 256 + threadIdx.x;          // 65536 float4s
            p1bf[t] = pack4(((const float4v*)proj1)[t]);
        } else {
            int t = (b - pb - 256) * 256 + threadIdx.x;    // 16384 float4s
            p2bf[t] = pack4(((const float4v*)proj2)[t]);
        }
        return;
    }
    int i = b * blockDim.x + threadIdx.x;
    int lane = threadIdx.x & 63;
    int id = (i < n) ? ids[i] : -1;
    bool is0 = (i < n) && (id < 20000);
    bool is1 = (i < n) && (id >= 20000) && (id < 60000);
    bool is2 = (i < n) && (id >= 60000);
    unsigned long long ltmask = (lane == 0) ? 0ull : (~0ull >> (64 - lane));

    unsigned long long m;
    m = __ballot(is0);
    if (m) {
        int leader = __ffsll(m) - 1;
        int base = 0;
        if (lane == leader) base = atomicAdd(&cnt[2], __popcll(m));
        base = __shfl(base, leader);
        if (is0) l0[base + __popcll(m & ltmask)] = i;
    }
    m = __ballot(is1);
    if (m) {
        int leader = __ffsll(m) - 1;
        int base = 0;
        if (lane == leader) base = atomicAdd(&cnt[0], __popcll(m));
        base = __shfl(base, leader);
        if (is1) l1[base + __popcll(m & ltmask)] = i;
    }
    m = __ballot(is2);
    if (m) {
        int leader = __ffsll(m) - 1;
        int base = 0;
        if (lane == leader) base = atomicAdd(&cnt[1], __popcll(m));
        base = __shfl(base, leader);
        if (is2) l2[base + __popcll(m & ltmask)] = i;
    }
}

// -------------------------- projected-cluster GEMM tile ---------------------
// Tile: 32 gathered tokens x 1024 dims, 8 waves (512 thr). Wave w owns dims
// [w*128, w*128+128) as 8 MFMA n-tiles. A gathered fp32->bf16 on the fly;
// B is pre-converted bf16 (L2-resident: proj1bf=512KB, proj2bf=128KB).
// MFMA 16x16x32 bf16 fragment layouts (verified m89 mappings):
//   A: lane holds A[m = lane&15][k = (lane>>4)*8 + j], j=0..7
//   B: lane holds B[k = (lane>>4)*8 + j][n = lane&15]  (= P[n][k], row-major P)
//   D: acc[reg r] = D[row = (lane>>4)*4 + r][col = lane&15]
template<int K, int START>
__device__ __forceinline__
void gemm_tile(int tile,
               const int* __restrict__ ids,
               const float* __restrict__ table,   // [rows, K] fp32
               const short* __restrict__ pbf,     // [1024, K] bf16
               const int* __restrict__ list,
               int count,
               float* __restrict__ out,
               int* s_tok, int* s_loc)
{
    const int m_base = tile * 32;
    const int tid = threadIdx.x;
    if (tid < 32) {
        int m   = m_base + tid;
        int tok = (m < count) ? list[m] : -1;
        s_tok[tid] = tok;
        s_loc[tid] = (tok >= 0) ? (ids[tok] - START) : 0;
    }
    __syncthreads();

    const int lane = tid & 63;
    const int wave = tid >> 6;     // 0..7
    const int col  = lane & 15;
    const int quad = lane >> 4;    // 0..3

    const float* arow0 = table + (size_t)s_loc[col]      * K + quad * 8;
    const float* arow1 = table + (size_t)s_loc[16 + col] * K + quad * 8;
    const short* bbase = pbf   + (size_t)(wave * 128 + col) * K + quad * 8;

    float4v acc0[8], acc1[8];
#pragma unroll
    for (int i = 0; i < 8; i++) {
        acc0[i] = (float4v){0.f, 0.f, 0.f, 0.f};
        acc1[i] = (float4v){0.f, 0.f, 0.f, 0.f};
    }

#pragma unroll
    for (int ks = 0; ks < K; ks += 32) {
        short8 a0 = cvt8(*(const float4v*)(arow0 + ks),
                         *(const float4v*)(arow0 + ks + 4));
        short8 a1 = cvt8(*(const float4v*)(arow1 + ks),
                         *(const float4v*)(arow1 + ks + 4));
#pragma unroll
        for (int nt = 0; nt < 8; nt++) {
            short8 b = *(const short8*)(bbase + (size_t)nt * 16 * K + ks);
            acc0[nt] = __builtin_amdgcn_mfma_f32_16x16x32_bf16(a0, b, acc0[nt], 0, 0, 0);
            acc1[nt] = __builtin_amdgcn_mfma_f32_16x16x32_bf16(a1, b, acc1[nt], 0, 0, 0);
        }
    }

#pragma unroll
    for (int r = 0; r < 4; r++) {
        int row = quad * 4 + r;
        if (m_base + row < count) {
            float* orow = out + (size_t)s_tok[row] * D_MODEL + wave * 128 + col;
#pragma unroll
            for (int nt = 0; nt < 8; nt++) orow[nt * 16] = acc0[nt][r] * 32.0f;
        }
        if (m_base + 16 + row < count) {
            float* orow = out + (size_t)s_tok[16 + row] * D_MODEL + wave * 128 + col;
#pragma unroll
            for (int nt = 0; nt < 8; nt++) orow[nt * 16] = acc1[nt][r] * 32.0f;
        }
    }
    __syncthreads();   // s_tok/s_loc reused by next grid-stride iteration
}

// -------------------------- cluster-0 copy item (2 rows / 512 thr) ----------
__device__ __forceinline__
void copy_item(int item, const int* __restrict__ ids,
               const int* __restrict__ l0, int count0,
               const float* __restrict__ emb0, float* __restrict__ out)
{
    int r = item * 2 + (threadIdx.x >> 8);       // two rows per item
    if (r < count0) {
        int t  = l0[r];
        int id = ids[t];   // emb0 row 0 is all-zero -> padding needs no special case
        const float4v* src = (const float4v*)(emb0 + (size_t)id * D_MODEL);
        float4v*       dst = (float4v*)(out + (size_t)t * D_MODEL);
        int c = threadIdx.x & 255;
        dst[c] = src[c] * 32.0f;                 // sqrt(1024)
    }
}

// -------------------------- fused consumer ----------------------------------
// One grid-stride kernel over a runtime work-list:
//   items [0, t1)          : cluster-1 GEMM tiles (K=256)  -- long poles first
//   items [t1, t1+t2)      : cluster-2 GEMM tiles (K=64)
//   items [t1+t2, total)   : cluster-0 row-pair copies
// All items write disjoint out rows; lists/cnt/projbf produced by prep_k.
__global__ __launch_bounds__(512)
void fused_main(const int* __restrict__ ids,
                const float* __restrict__ emb0,
                const float* __restrict__ emb1,
                const float* __restrict__ emb2,
                const short* __restrict__ p1bf,
                const short* __restrict__ p2bf,
                const int* __restrict__ l0,
                const int* __restrict__ l1,
                const int* __restrict__ l2,
                const int* __restrict__ cnt,
                float* __restrict__ out)
{
    __shared__ int s_tok[32];
    __shared__ int s_loc[32];

    const int c1 = cnt[0];
    const int c2 = cnt[1];
    const int c0 = cnt[2];
    const int t1 = (c1 + 31) >> 5;
    const int t2 = (c2 + 31) >> 5;
    const int tc = (c0 + 1) >> 1;
    const int total = t1 + t2 + tc;

    for (int w = blockIdx.x; w < total; w += gridDim.x) {
        if (w < t1) {
            gemm_tile<256, 20000>(w, ids, emb1, p1bf, l1, c1, out, s_tok, s_loc);
        } else if (w < t1 + t2) {
            gemm_tile<64, 60000>(w - t1, ids, emb2, p2bf, l2, c2, out, s_tok, s_loc);
        } else {
            copy_item(w - t1 - t2, ids, l0, c0, emb0, out);
        }
    }
}

// ---------------------------------------------------------------------------
extern "C" void kernel_launch(void* const* d_in, const int* in_sizes, int n_in,
                              void* d_out, int out_size, void* d_ws, size_t ws_size,
                              hipStream_t stream)
{
    const int*   ids   = (const int*)  d_in[0];
    const float* emb0  = (const float*)d_in[1];
    const float* emb1  = (const float*)d_in[2];
    const float* emb2  = (const float*)d_in[3];
    const float* proj1 = (const float*)d_in[4];
    const float* proj2 = (const float*)d_in[5];
    float*       out   = (float*)d_out;
    const int n = in_sizes[0];                 // 32768 tokens

    // ws layout: [0,256) counters | l0,l1,l2 (n ints each) | proj1bf | proj2bf
    int*   cnt  = (int*)d_ws;
    int*   l0   = (int*)((char*)d_ws + 256);
    int*   l1   = l0 + n;
    int*   l2   = l1 + n;
    size_t poff = (256 + (size_t)3 * n * 4 + 255) & ~(size_t)255;
    short* p1bf = (short*)((char*)d_ws + poff);
    short* p2bf = p1bf + 1024 * 256;

    const int pb = (n + 255) / 256;            // partition blocks

    hipMemsetAsync(cnt, 0, 4 * sizeof(int), stream);
    prep_k<<<pb + 256 + 64, 256, 0, stream>>>(ids, n, pb, cnt, l0, l1, l2,
                                              proj1, proj2,
                                              (uint2v*)p1bf, (uint2v*)p2bf);
    fused_main<<<2048, 512, 0, stream>>>(ids, emb0, emb1, emb2,
                                         p1bf, p2bf, l0, l1, l2, cnt, out);
}

// Round 2
// 288.204 us; speedup vs baseline: 1.0693x; 1.0604x over previous
//
#include <hip/hip_runtime.h>
#include <hip/hip_bf16.h>

// ---------------------------------------------------------------------------
// AdaptiveEmbedding: 3-cluster adaptive input embedding.
//   ids in [0,20000)      -> emb0[id] (1024), padding row 0 is zero
//   ids in [20000,60000)  -> proj1(1024x256) @ emb1[id-20000]
//   ids in [60000,128000) -> proj2(1024x64)  @ emb2[id-60000]
// Scaled by sqrt(1024)=32. Each out row written exactly once.
//
// R4 -> R5: fused_main measured 100us / 1.9TB/s, but TOTAL stayed ~305us ->
// ~200us is outside the consumer. Inference: prep_k's per-WAVE compaction
// atomics (128 blk x 4 waves x 3 clusters = 1536 same-address device atomics,
// each with a dependent base read) serialize at the coherence point. Fix:
// 1024-thread partition blocks with LDS two-level aggregation -> ONE
// atomicAdd per block per cluster (96 total, 16x fewer), bases fanned out
// through LDS. Everything else unchanged.
// ---------------------------------------------------------------------------

typedef __attribute__((ext_vector_type(4))) float        float4v;
typedef __attribute__((ext_vector_type(8))) short        short8;
typedef __attribute__((ext_vector_type(2))) unsigned int uint2v;

#define D_MODEL 1024

__device__ __forceinline__ short f2bf(float x) {
    // round-to-nearest-even f32 -> bf16 (inputs are finite)
    unsigned u = __builtin_bit_cast(unsigned, x);
    unsigned r = u + 0x7fffu + ((u >> 16) & 1u);
    return (short)(r >> 16);
}

__device__ __forceinline__ short8 cvt8(float4v a, float4v b) {
    short8 r;
    r[0] = f2bf(a[0]); r[1] = f2bf(a[1]); r[2] = f2bf(a[2]); r[3] = f2bf(a[3]);
    r[4] = f2bf(b[0]); r[5] = f2bf(b[1]); r[6] = f2bf(b[2]); r[7] = f2bf(b[3]);
    return r;
}

__device__ __forceinline__ uint2v pack4(float4v v) {
    uint2v r;
    r[0] = (unsigned)(unsigned short)f2bf(v[0]) | ((unsigned)(unsigned short)f2bf(v[1]) << 16);
    r[1] = (unsigned)(unsigned short)f2bf(v[2]) | ((unsigned)(unsigned short)f2bf(v[3]) << 16);
    return r;
}

// ------------------ partition (3 lists) + proj->bf16 conversion -------------
// 1024-thread blocks.
// blocks [0, pb)           : partition of ids into l0/l1/l2.
//   two-level aggregation: ballot -> per-wave counts in LDS -> per-block scan
//   -> ONE atomicAdd per block per cluster -> fan bases out via LDS.
// blocks [pb, pb+64)       : proj1 (1024x256 fp32) -> bf16, 1 float4/thread
// blocks [pb+64, pb+80)    : proj2 (1024x64  fp32) -> bf16
__global__ __launch_bounds__(1024)
void prep_k(const int* __restrict__ ids, int n, int pb,
            int* __restrict__ cnt,
            int* __restrict__ l0, int* __restrict__ l1, int* __restrict__ l2,
            const float* __restrict__ proj1, const float* __restrict__ proj2,
            uint2v* __restrict__ p1bf, uint2v* __restrict__ p2bf)
{
    const int b = blockIdx.x;
    if (b >= pb) {
        int bb = b - pb;
        if (bb < 64) {
            int t = bb * 1024 + threadIdx.x;               // 65536 float4s
            p1bf[t] = pack4(((const float4v*)proj1)[t]);
        } else {
            int t = (bb - 64) * 1024 + threadIdx.x;        // 16384 float4s
            p2bf[t] = pack4(((const float4v*)proj2)[t]);
        }
        return;
    }

    __shared__ int s_wcnt[16][3];    // per-wave counts
    __shared__ int s_wbase[16][3];   // exclusive scan over waves
    __shared__ int s_base[3];        // block's global base per cluster

    const int tid  = threadIdx.x;
    const int wave = tid >> 6;       // 0..15
    const int lane = tid & 63;
    const int i    = b * 1024 + tid;

    int id = (i < n) ? ids[i] : -1;
    bool is0 = (i < n) && (id < 20000);
    bool is1 = (i < n) && (id >= 20000) && (id < 60000);
    bool is2 = (i < n) && (id >= 60000);
    unsigned long long ltmask = (lane == 0) ? 0ull : (~0ull >> (64 - lane));

    unsigned long long m0 = __ballot(is0);
    unsigned long long m1 = __ballot(is1);
    unsigned long long m2 = __ballot(is2);
    if (lane == 0) {
        s_wcnt[wave][0] = __popcll(m0);
        s_wcnt[wave][1] = __popcll(m1);
        s_wcnt[wave][2] = __popcll(m2);
    }
    __syncthreads();

    if (tid < 3) {
        const int c = tid;
        int run = 0;
#pragma unroll
        for (int w = 0; w < 16; w++) { s_wbase[w][c] = run; run += s_wcnt[w][c]; }
        // counter mapping kept from R3: cluster1->cnt[0], cluster2->cnt[1], cluster0->cnt[2]
        const int gidx = (c == 0) ? 2 : (c - 1);
        s_base[c] = atomicAdd(&cnt[gidx], run);
    }
    __syncthreads();

    if (is0) l0[s_base[0] + s_wbase[wave][0] + __popcll(m0 & ltmask)] = i;
    if (is1) l1[s_base[1] + s_wbase[wave][1] + __popcll(m1 & ltmask)] = i;
    if (is2) l2[s_base[2] + s_wbase[wave][2] + __popcll(m2 & ltmask)] = i;
}

// -------------------------- projected-cluster GEMM tile ---------------------
// Tile: 32 gathered tokens x 1024 dims, 8 waves (512 thr). Wave w owns dims
// [w*128, w*128+128) as 8 MFMA n-tiles. A gathered fp32->bf16 on the fly;
// B is pre-converted bf16 (L2-resident: proj1bf=512KB, proj2bf=128KB).
// MFMA 16x16x32 bf16 fragment layouts (verified m89 mappings):
//   A: lane holds A[m = lane&15][k = (lane>>4)*8 + j], j=0..7
//   B: lane holds B[k = (lane>>4)*8 + j][n = lane&15]  (= P[n][k], row-major P)
//   D: acc[reg r] = D[row = (lane>>4)*4 + r][col = lane&15]
template<int K, int START>
__device__ __forceinline__
void gemm_tile(int tile,
               const int* __restrict__ ids,
               const float* __restrict__ table,   // [rows, K] fp32
               const short* __restrict__ pbf,     // [1024, K] bf16
               const int* __restrict__ list,
               int count,
               float* __restrict__ out,
               int* s_tok, int* s_loc)
{
    const int m_base = tile * 32;
    const int tid = threadIdx.x;
    if (tid < 32) {
        int m   = m_base + tid;
        int tok = (m < count) ? list[m] : -1;
        s_tok[tid] = tok;
        s_loc[tid] = (tok >= 0) ? (ids[tok] - START) : 0;
    }
    __syncthreads();

    const int lane = tid & 63;
    const int wave = tid >> 6;     // 0..7
    const int col  = lane & 15;
    const int quad = lane >> 4;    // 0..3

    const float* arow0 = table + (size_t)s_loc[col]      * K + quad * 8;
    const float* arow1 = table + (size_t)s_loc[16 + col] * K + quad * 8;
    const short* bbase = pbf   + (size_t)(wave * 128 + col) * K + quad * 8;

    float4v acc0[8], acc1[8];
#pragma unroll
    for (int i = 0; i < 8; i++) {
        acc0[i] = (float4v){0.f, 0.f, 0.f, 0.f};
        acc1[i] = (float4v){0.f, 0.f, 0.f, 0.f};
    }

#pragma unroll
    for (int ks = 0; ks < K; ks += 32) {
        short8 a0 = cvt8(*(const float4v*)(arow0 + ks),
                         *(const float4v*)(arow0 + ks + 4));
        short8 a1 = cvt8(*(const float4v*)(arow1 + ks),
                         *(const float4v*)(arow1 + ks + 4));
#pragma unroll
        for (int nt = 0; nt < 8; nt++) {
            short8 b = *(const short8*)(bbase + (size_t)nt * 16 * K + ks);
            acc0[nt] = __builtin_amdgcn_mfma_f32_16x16x32_bf16(a0, b, acc0[nt], 0, 0, 0);
            acc1[nt] = __builtin_amdgcn_mfma_f32_16x16x32_bf16(a1, b, acc1[nt], 0, 0, 0);
        }
    }

#pragma unroll
    for (int r = 0; r < 4; r++) {
        int row = quad * 4 + r;
        if (m_base + row < count) {
            float* orow = out + (size_t)s_tok[row] * D_MODEL + wave * 128 + col;
#pragma unroll
            for (int nt = 0; nt < 8; nt++) orow[nt * 16] = acc0[nt][r] * 32.0f;
        }
        if (m_base + 16 + row < count) {
            float* orow = out + (size_t)s_tok[16 + row] * D_MODEL + wave * 128 + col;
#pragma unroll
            for (int nt = 0; nt < 8; nt++) orow[nt * 16] = acc1[nt][r] * 32.0f;
        }
    }
    __syncthreads();   // s_tok/s_loc reused by next grid-stride iteration
}

// -------------------------- cluster-0 copy item (2 rows / 512 thr) ----------
__device__ __forceinline__
void copy_item(int item, const int* __restrict__ ids,
               const int* __restrict__ l0, int count0,
               const float* __restrict__ emb0, float* __restrict__ out)
{
    int r = item * 2 + (threadIdx.x >> 8);       // two rows per item
    if (r < count0) {
        int t  = l0[r];
        int id = ids[t];   // emb0 row 0 is all-zero -> padding needs no special case
        const float4v* src = (const float4v*)(emb0 + (size_t)id * D_MODEL);
        float4v*       dst = (float4v*)(out + (size_t)t * D_MODEL);
        int c = threadIdx.x & 255;
        dst[c] = src[c] * 32.0f;                 // sqrt(1024)
    }
}

// -------------------------- fused consumer ----------------------------------
// One grid-stride kernel over a runtime work-list:
//   items [0, t1)          : cluster-1 GEMM tiles (K=256)  -- long poles first
//   items [t1, t1+t2)      : cluster-2 GEMM tiles (K=64)
//   items [t1+t2, total)   : cluster-0 row-pair copies
// All items write disjoint out rows; lists/cnt/projbf produced by prep_k.
__global__ __launch_bounds__(512)
void fused_main(const int* __restrict__ ids,
                const float* __restrict__ emb0,
                const float* __restrict__ emb1,
                const float* __restrict__ emb2,
                const short* __restrict__ p1bf,
                const short* __restrict__ p2bf,
                const int* __restrict__ l0,
                const int* __restrict__ l1,
                const int* __restrict__ l2,
                const int* __restrict__ cnt,
                float* __restrict__ out)
{
    __shared__ int s_tok[32];
    __shared__ int s_loc[32];

    const int c1 = cnt[0];
    const int c2 = cnt[1];
    const int c0 = cnt[2];
    const int t1 = (c1 + 31) >> 5;
    const int t2 = (c2 + 31) >> 5;
    const int tc = (c0 + 1) >> 1;
    const int total = t1 + t2 + tc;

    for (int w = blockIdx.x; w < total; w += gridDim.x) {
        if (w < t1) {
            gemm_tile<256, 20000>(w, ids, emb1, p1bf, l1, c1, out, s_tok, s_loc);
        } else if (w < t1 + t2) {
            gemm_tile<64, 60000>(w - t1, ids, emb2, p2bf, l2, c2, out, s_tok, s_loc);
        } else {
            copy_item(w - t1 - t2, ids, l0, c0, emb0, out);
        }
    }
}

// ---------------------------------------------------------------------------
extern "C" void kernel_launch(void* const* d_in, const int* in_sizes, int n_in,
                              void* d_out, int out_size, void* d_ws, size_t ws_size,
                              hipStream_t stream)
{
    const int*   ids   = (const int*)  d_in[0];
    const float* emb0  = (const float*)d_in[1];
    const float* emb1  = (const float*)d_in[2];
    const float* emb2  = (const float*)d_in[3];
    const float* proj1 = (const float*)d_in[4];
    const float* proj2 = (const float*)d_in[5];
    float*       out   = (float*)d_out;
    const int n = in_sizes[0];                 // 32768 tokens

    // ws layout: [0,256) counters | l0,l1,l2 (n ints each) | proj1bf | proj2bf
    int*   cnt  = (int*)d_ws;
    int*   l0   = (int*)((char*)d_ws + 256);
    int*   l1   = l0 + n;
    int*   l2   = l1 + n;
    size_t poff = (256 + (size_t)3 * n * 4 + 255) & ~(size_t)255;
    short* p1bf = (short*)((char*)d_ws + poff);
    short* p2bf = p1bf + 1024 * 256;

    const int pb = (n + 1023) / 1024;          // partition blocks (1024 thr)

    hipMemsetAsync(cnt, 0, 4 * sizeof(int), stream);
    prep_k<<<pb + 64 + 16, 1024, 0, stream>>>(ids, n, pb, cnt, l0, l1, l2,
                                              proj1, proj2,
                                              (uint2v*)p1bf, (uint2v*)p2bf);
    fused_main<<<2048, 512, 0, stream>>>(ids, emb0, emb1, emb2,
                                         p1bf, p2bf, l0, l1, l2, cnt, out);
}

// Round 3
// 272.789 us; speedup vs baseline: 1.1298x; 1.0565x over previous
//
#include <hip/hip_runtime.h>
#include <hip/hip_bf16.h>

// ---------------------------------------------------------------------------
// AdaptiveEmbedding: 3-cluster adaptive input embedding.
//   ids in [0,20000)      -> emb0[id] (1024), padding row 0 is zero
//   ids in [20000,60000)  -> proj1(1024x256) @ emb1[id-20000]
//   ids in [60000,128000) -> proj2(1024x64)  @ emb2[id-60000]
// Scaled by sqrt(1024)=32. Each out row written exactly once.
//
// R5 -> R6: fused_main was 110us @ 1.7TB/s with MfmaUtil 2.6 / VALU 6.4 /
// Occ 21 -- all pipes idle => per-lane A-gather latency chains (8 scattered
// 32-B fp32 loads per tile at ~900cy HBM latency, serialized because VGPR=128
// can't hold the pipeline; plus 8x redundant across waves). Fix: LDS-stage
// the 32-row A tile ONCE per tile (coalesced 1KB/row cooperative loads,
// fp32->bf16 packed on stage, +8-short row padding to break the 512-B-stride
// bank conflict); K-loop A-fragments become single ds_read_b128, no global
// gather, no cvt. B stays global (L2-resident).
// ---------------------------------------------------------------------------

typedef __attribute__((ext_vector_type(4))) float        float4v;
typedef __attribute__((ext_vector_type(8))) short        short8;
typedef __attribute__((ext_vector_type(2))) unsigned int uint2v;

#define D_MODEL 1024

__device__ __forceinline__ short f2bf(float x) {
    // round-to-nearest-even f32 -> bf16 (inputs are finite)
    unsigned u = __builtin_bit_cast(unsigned, x);
    unsigned r = u + 0x7fffu + ((u >> 16) & 1u);
    return (short)(r >> 16);
}

__device__ __forceinline__ uint2v pack4(float4v v) {
    uint2v r;
    r[0] = (unsigned)(unsigned short)f2bf(v[0]) | ((unsigned)(unsigned short)f2bf(v[1]) << 16);
    r[1] = (unsigned)(unsigned short)f2bf(v[2]) | ((unsigned)(unsigned short)f2bf(v[3]) << 16);
    return r;
}

// ------------------ partition (3 lists) + proj->bf16 conversion -------------
// 1024-thread blocks.
// blocks [0, pb)           : partition of ids into l0/l1/l2.
//   two-level aggregation: ballot -> per-wave counts in LDS -> per-block scan
//   -> ONE atomicAdd per block per cluster -> fan bases out via LDS.
// blocks [pb, pb+64)       : proj1 (1024x256 fp32) -> bf16, 1 float4/thread
// blocks [pb+64, pb+80)    : proj2 (1024x64  fp32) -> bf16
__global__ __launch_bounds__(1024)
void prep_k(const int* __restrict__ ids, int n, int pb,
            int* __restrict__ cnt,
            int* __restrict__ l0, int* __restrict__ l1, int* __restrict__ l2,
            const float* __restrict__ proj1, const float* __restrict__ proj2,
            uint2v* __restrict__ p1bf, uint2v* __restrict__ p2bf)
{
    const int b = blockIdx.x;
    if (b >= pb) {
        int bb = b - pb;
        if (bb < 64) {
            int t = bb * 1024 + threadIdx.x;               // 65536 float4s
            p1bf[t] = pack4(((const float4v*)proj1)[t]);
        } else {
            int t = (bb - 64) * 1024 + threadIdx.x;        // 16384 float4s
            p2bf[t] = pack4(((const float4v*)proj2)[t]);
        }
        return;
    }

    __shared__ int s_wcnt[16][3];    // per-wave counts
    __shared__ int s_wbase[16][3];   // exclusive scan over waves
    __shared__ int s_base[3];        // block's global base per cluster

    const int tid  = threadIdx.x;
    const int wave = tid >> 6;       // 0..15
    const int lane = tid & 63;
    const int i    = b * 1024 + tid;

    int id = (i < n) ? ids[i] : -1;
    bool is0 = (i < n) && (id < 20000);
    bool is1 = (i < n) && (id >= 20000) && (id < 60000);
    bool is2 = (i < n) && (id >= 60000);
    unsigned long long ltmask = (lane == 0) ? 0ull : (~0ull >> (64 - lane));

    unsigned long long m0 = __ballot(is0);
    unsigned long long m1 = __ballot(is1);
    unsigned long long m2 = __ballot(is2);
    if (lane == 0) {
        s_wcnt[wave][0] = __popcll(m0);
        s_wcnt[wave][1] = __popcll(m1);
        s_wcnt[wave][2] = __popcll(m2);
    }
    __syncthreads();

    if (tid < 3) {
        const int c = tid;
        int run = 0;
#pragma unroll
        for (int w = 0; w < 16; w++) { s_wbase[w][c] = run; run += s_wcnt[w][c]; }
        // counter mapping: cluster1->cnt[0], cluster2->cnt[1], cluster0->cnt[2]
        const int gidx = (c == 0) ? 2 : (c - 1);
        s_base[c] = atomicAdd(&cnt[gidx], run);
    }
    __syncthreads();

    if (is0) l0[s_base[0] + s_wbase[wave][0] + __popcll(m0 & ltmask)] = i;
    if (is1) l1[s_base[1] + s_wbase[wave][1] + __popcll(m1 & ltmask)] = i;
    if (is2) l2[s_base[2] + s_wbase[wave][2] + __popcll(m2 & ltmask)] = i;
}

// -------------------------- projected-cluster GEMM tile ---------------------
// Tile: 32 gathered tokens x 1024 dims, 8 waves (512 thr). Wave w owns dims
// [w*128, w*128+128) as 8 MFMA n-tiles.
// A tile is LDS-staged once (coalesced, fp32->bf16 on stage); row stride is
// K+8 shorts so fragment reads at 16-lane row-stride hit <=2-way banks (free).
// B is pre-converted bf16 in ws (L2-resident: 512KB / 128KB).
// MFMA 16x16x32 bf16 fragment layouts (verified m89 mappings):
//   A: lane holds A[m = lane&15][k = (lane>>4)*8 + j], j=0..7
//   B: lane holds B[k = (lane>>4)*8 + j][n = lane&15]  (= P[n][k], row-major P)
//   D: acc[reg r] = D[row = (lane>>4)*4 + r][col = lane&15]
template<int K, int START>
__device__ __forceinline__
void gemm_tile(int tile,
               const int* __restrict__ ids,
               const float* __restrict__ table,   // [rows, K] fp32
               const short* __restrict__ pbf,     // [1024, K] bf16
               const int* __restrict__ list,
               int count,
               float* __restrict__ out,
               int* s_tok, int* s_loc, short* s_a)
{
    constexpr int PK = K + 8;          // padded LDS row stride (shorts)
    const int m_base = tile * 32;
    const int tid = threadIdx.x;
    if (tid < 32) {
        int m   = m_base + tid;
        int tok = (m < count) ? list[m] : -1;
        s_tok[tid] = tok;
        s_loc[tid] = (tok >= 0) ? (ids[tok] - START) : 0;
    }
    __syncthreads();

    // ---- stage A: 32 rows x K fp32 -> bf16 LDS. 16 thr/row, 64B/thr (K=256)
    {
        const int row = tid >> 4;                       // 0..31
        const int c   = tid & 15;
        const float* src = table + (size_t)s_loc[row] * K + c * (K / 16);
        short*       dst = s_a + row * PK + c * (K / 16);
        if constexpr (K == 256) {
            const float4v* s4 = (const float4v*)src;
            float4v f0 = s4[0], f1 = s4[1], f2 = s4[2], f3 = s4[3];
            uint2v* d2 = (uint2v*)dst;
            d2[0] = pack4(f0); d2[1] = pack4(f1);
            d2[2] = pack4(f2); d2[3] = pack4(f3);
        } else {                                        // K == 64: 16B/thr
            float4v f0 = *(const float4v*)src;
            *(uint2v*)dst = pack4(f0);
        }
    }
    __syncthreads();

    const int lane = tid & 63;
    const int wave = tid >> 6;     // 0..7
    const int col  = lane & 15;
    const int quad = lane >> 4;    // 0..3

    const short* arow0 = s_a + col * PK        + quad * 8;
    const short* arow1 = s_a + (col + 16) * PK + quad * 8;
    const short* bbase = pbf + (size_t)(wave * 128 + col) * K + quad * 8;

    float4v acc0[8], acc1[8];
#pragma unroll
    for (int i = 0; i < 8; i++) {
        acc0[i] = (float4v){0.f, 0.f, 0.f, 0.f};
        acc1[i] = (float4v){0.f, 0.f, 0.f, 0.f};
    }

#pragma unroll
    for (int ks = 0; ks < K; ks += 32) {
        short8 a0 = *(const short8*)(arow0 + ks);   // ds_read_b128
        short8 a1 = *(const short8*)(arow1 + ks);
#pragma unroll
        for (int nt = 0; nt < 8; nt++) {
            short8 b = *(const short8*)(bbase + (size_t)nt * 16 * K + ks);
            acc0[nt] = __builtin_amdgcn_mfma_f32_16x16x32_bf16(a0, b, acc0[nt], 0, 0, 0);
            acc1[nt] = __builtin_amdgcn_mfma_f32_16x16x32_bf16(a1, b, acc1[nt], 0, 0, 0);
        }
    }

#pragma unroll
    for (int r = 0; r < 4; r++) {
        int row = quad * 4 + r;
        if (m_base + row < count) {
            float* orow = out + (size_t)s_tok[row] * D_MODEL + wave * 128 + col;
#pragma unroll
            for (int nt = 0; nt < 8; nt++) orow[nt * 16] = acc0[nt][r] * 32.0f;
        }
        if (m_base + 16 + row < count) {
            float* orow = out + (size_t)s_tok[16 + row] * D_MODEL + wave * 128 + col;
#pragma unroll
            for (int nt = 0; nt < 8; nt++) orow[nt * 16] = acc1[nt][r] * 32.0f;
        }
    }
    __syncthreads();   // s_tok/s_loc/s_a reused by next grid-stride iteration
}

// -------------------------- cluster-0 copy item (2 rows / 512 thr) ----------
__device__ __forceinline__
void copy_item(int item, const int* __restrict__ ids,
               const int* __restrict__ l0, int count0,
               const float* __restrict__ emb0, float* __restrict__ out)
{
    int r = item * 2 + (threadIdx.x >> 8);       // two rows per item
    if (r < count0) {
        int t  = l0[r];
        int id = ids[t];   // emb0 row 0 is all-zero -> padding needs no special case
        const float4v* src = (const float4v*)(emb0 + (size_t)id * D_MODEL);
        float4v*       dst = (float4v*)(out + (size_t)t * D_MODEL);
        int c = threadIdx.x & 255;
        dst[c] = src[c] * 32.0f;                 // sqrt(1024)
    }
}

// -------------------------- fused consumer ----------------------------------
// One grid-stride kernel over a runtime work-list:
//   items [0, t1)          : cluster-1 GEMM tiles (K=256)  -- long poles first
//   items [t1, t1+t2)      : cluster-2 GEMM tiles (K=64)
//   items [t1+t2, total)   : cluster-0 row-pair copies
// All items write disjoint out rows; lists/cnt/projbf produced by prep_k.
__global__ __launch_bounds__(512)
void fused_main(const int* __restrict__ ids,
                const float* __restrict__ emb0,
                const float* __restrict__ emb1,
                const float* __restrict__ emb2,
                const short* __restrict__ p1bf,
                const short* __restrict__ p2bf,
                const int* __restrict__ l0,
                const int* __restrict__ l1,
                const int* __restrict__ l2,
                const int* __restrict__ cnt,
                float* __restrict__ out)
{
    __shared__ int   s_tok[32];
    __shared__ int   s_loc[32];
    __shared__ short s_a[32 * 264];   // 33 KB: A tile, bf16, padded rows

    const int c1 = cnt[0];
    const int c2 = cnt[1];
    const int c0 = cnt[2];
    const int t1 = (c1 + 31) >> 5;
    const int t2 = (c2 + 31) >> 5;
    const int tc = (c0 + 1) >> 1;
    const int total = t1 + t2 + tc;

    for (int w = blockIdx.x; w < total; w += gridDim.x) {
        if (w < t1) {
            gemm_tile<256, 20000>(w, ids, emb1, p1bf, l1, c1, out, s_tok, s_loc, s_a);
        } else if (w < t1 + t2) {
            gemm_tile<64, 60000>(w - t1, ids, emb2, p2bf, l2, c2, out, s_tok, s_loc, s_a);
        } else {
            copy_item(w - t1 - t2, ids, l0, c0, emb0, out);
        }
    }
}

// ---------------------------------------------------------------------------
extern "C" void kernel_launch(void* const* d_in, const int* in_sizes, int n_in,
                              void* d_out, int out_size, void* d_ws, size_t ws_size,
                              hipStream_t stream)
{
    const int*   ids   = (const int*)  d_in[0];
    const float* emb0  = (const float*)d_in[1];
    const float* emb1  = (const float*)d_in[2];
    const float* emb2  = (const float*)d_in[3];
    const float* proj1 = (const float*)d_in[4];
    const float* proj2 = (const float*)d_in[5];
    float*       out   = (float*)d_out;
    const int n = in_sizes[0];                 // 32768 tokens

    // ws layout: [0,256) counters | l0,l1,l2 (n ints each) | proj1bf | proj2bf
    int*   cnt  = (int*)d_ws;
    int*   l0   = (int*)((char*)d_ws + 256);
    int*   l1   = l0 + n;
    int*   l2   = l1 + n;
    size_t poff = (256 + (size_t)3 * n * 4 + 255) & ~(size_t)255;
    short* p1bf = (short*)((char*)d_ws + poff);
    short* p2bf = p1bf + 1024 * 256;

    const int pb = (n + 1023) / 1024;          // partition blocks (1024 thr)

    hipMemsetAsync(cnt, 0, 4 * sizeof(int), stream);
    prep_k<<<pb + 64 + 16, 1024, 0, stream>>>(ids, n, pb, cnt, l0, l1, l2,
                                              proj1, proj2,
                                              (uint2v*)p1bf, (uint2v*)p2bf);
    fused_main<<<2048, 512, 0, stream>>>(ids, emb0, emb1, emb2,
                                         p1bf, p2bf, l0, l1, l2, cnt, out);
}